// Round 7
// baseline (100.456 us; speedup 1.0000x reference)
//
#include <hip/hip_runtime.h>
#include <float.h>
#include <math.h>

// Problem constants (fixed by reference setup_inputs)
constexpr int NQ = 2048;    // queries
constexpr int ND = 65536;   // data points
constexpr int D  = 16;      // dims

// ---- MFMA-path tiling (16x16x32, K=32 hi/lo packing, norm folded) ----
// Chunk = 512 points = 32 tiles of 16 points; packed 1 KB/tile -> 32 KB LDS.
// Block = 4 waves; each wave = 32 queries (2 row-tiles of 16) x full chunk.
// grid = (NQ/128 = 16, SCH = 128) = 2048 blocks.
constexpr int SCH  = 128;           // point chunks (grid.y)
constexpr int CP   = ND / SCH;      // 512 points per chunk
constexpr int TPC  = CP / 16;       // 32 point-tiles per chunk
constexpr int NPR  = TPC / 2;       // 16 tile-pairs
constexpr int CHUNK_B = TPC * 1024; // 32768 B per packed chunk

typedef short bf16x8 __attribute__((ext_vector_type(8)));
typedef float f32x4  __attribute__((ext_vector_type(4)));

__device__ __forceinline__ unsigned short f2bf(float f) {  // RNE fp32->bf16
    unsigned u = __float_as_uint(f);
    u += 0x7FFFu + ((u >> 16) & 1u);
    return (unsigned short)(u >> 16);
}
__device__ __forceinline__ float bf2f(unsigned short h) {
    return __uint_as_float(((unsigned)h) << 16);
}

// ---------------------------------------------------------------------------
// Pack kernel: per point p build the K=32 column vector
//   slots 0..15  = ph (bf16 hi of all 16 dims)
//   slots 16..29 = pl (bf16 lo residual of dims 0..13)
//   slot  30     = nh (bf16 hi of -0.5*||p||^2)
//   slot  31     = nl (bf16 lo residual of the norm)
// stored in LANE-CONSUMPTION order: tile t (16 pts), entry (kg*16+n15)*16B,
// so lane l of a wave reads its whole B-frag with one ds_read_b128 at l*16.
// ---------------------------------------------------------------------------
__global__ __launch_bounds__(256) void pack_data(const float* __restrict__ data,
                                                 unsigned char* __restrict__ Ppk) {
    const int p = blockIdx.x * 256 + threadIdx.x;
    const float4* r4 = (const float4*)(data + (size_t)p * D);
    float4 a = r4[0], b = r4[1], c4 = r4[2], e = r4[3];
    const float v[16] = {a.x, a.y, a.z, a.w, b.x, b.y, b.z, b.w,
                         c4.x, c4.y, c4.z, c4.w, e.x, e.y, e.z, e.w};
    unsigned short slot[32];
    float n = 0.f;
#pragma unroll
    for (int k = 0; k < 16; ++k) {
        n = fmaf(v[k], v[k], n);
        unsigned short h = f2bf(v[k]);
        slot[k] = h;
        if (k < 14) slot[16 + k] = f2bf(v[k] - bf2f(h));   // lo residual
    }
    const float nn = -0.5f * n;
    unsigned short nh = f2bf(nn);
    slot[30] = nh;
    slot[31] = f2bf(nn - bf2f(nh));

    const int c   = p >> 9;        // chunk (512 pts)
    const int i   = p & 511;
    const int t   = i >> 4;        // tile (16 pts)
    const int n15 = i & 15;
    unsigned char* tb = Ppk + (size_t)c * CHUNK_B + (size_t)t * 1024;
    const uint4* s4 = (const uint4*)slot;
#pragma unroll
    for (int kg = 0; kg < 4; ++kg)
        *(uint4*)(tb + (size_t)(kg * 16 + n15) * 16) = s4[kg];
}

// ---------------------------------------------------------------------------
// Main kernel.  best[q] = max_p ( x.p - 0.5*||p||^2 )  (argmin dist2 == argmax)
// Per 16-pt tile: 1 ds_read_b128 + 4 MFMA (2 row-tiles x {hi,lo} chained) +
// 4 max/row-tile. C seeded from a PERSISTENT ZERO quad (norm folded into K)
// -> no per-tile C-init VALU at all.
// A-frag (M=16,K=32): lane l holds A[m=l&15][k=(l>>4)*8+j].
// A-hi = [xh(0..15) | xh(0..13) | 1 | 1]; A-lo = [xl(0..15) | xl(0..13) | 0 | 0].
// C/D: col(point)=l&15, row(query)=(l>>4)*4+reg  [m89, HW-verified].
// ---------------------------------------------------------------------------
__global__ __launch_bounds__(256, 4) void knn_mfma(const float* __restrict__ x,
                                                   const unsigned char* __restrict__ Ppk,
                                                   float* __restrict__ part) {
    __shared__ unsigned char smem[CHUNK_B];   // 32 KB

    const int tid = threadIdx.x;
    const int w   = tid >> 6;
    const int l   = tid & 63;
    const int kg  = l >> 4;        // k-group 0..3
    const int n15 = l & 15;
    const int qblock = blockIdx.x * 128;      // block covers 128 queries

    // ---- Stage chunk: 8 rounds x 256 threads x 16 B = 32 KB (coalesced) ----
    {
        const unsigned char* src = Ppk + (size_t)blockIdx.y * CHUNK_B;
#pragma unroll
        for (int r = 0; r < 8; ++r) {
            const int off = r * 4096 + tid * 16;
            *(uint4*)(smem + off) = *(const uint4*)(src + off);
        }
    }

    // ---- Build A fragments for 2 row-tiles (overlaps staging latency) ----
    bf16x8 Ah[2], Al[2];
#pragma unroll
    for (int rt = 0; rt < 2; ++rt) {
        const float* xr = x + (size_t)(qblock + w * 32 + rt * 16 + n15) * D + (kg & 1) * 8;
        float4 f0 = *(const float4*)xr;
        float4 f1 = *(const float4*)(xr + 4);
        const float xv[8] = {f0.x, f0.y, f0.z, f0.w, f1.x, f1.y, f1.z, f1.w};
#pragma unroll
        for (int j = 0; j < 8; ++j) {
            unsigned short h  = f2bf(xv[j]);
            unsigned short lo = f2bf(xv[j] - bf2f(h));
            if (kg == 3 && j >= 6) { h = 0x3F80; lo = 0; }   // the "1,1" / "0,0" slots
            Ah[rt][j] = (short)h;
            Al[rt][j] = (short)lo;
        }
    }

    __syncthreads();   // staging complete

    const f32x4 zeroq = {0.f, 0.f, 0.f, 0.f};   // persistent zero C seed
    f32x4 rb0 = {-FLT_MAX, -FLT_MAX, -FLT_MAX, -FLT_MAX};
    f32x4 rb1 = rb0;

#define LDB(t) (*(const bf16x8*)(smem + (size_t)(t) * 1024 + (size_t)l * 16))

    // ---- Tile-pair loop, ping-pong register prefetch ----
    bf16x8 Ba = LDB(0), Bb = LDB(1);
    for (int p = 0; p < NPR; ++p) {
        bf16x8 Na, Nb;
        if (p + 1 < NPR) { Na = LDB(2 * p + 2); Nb = LDB(2 * p + 3); }
        f32x4 cA0 = __builtin_amdgcn_mfma_f32_16x16x32_bf16(Ah[0], Ba, zeroq, 0, 0, 0);
        f32x4 cA1 = __builtin_amdgcn_mfma_f32_16x16x32_bf16(Ah[1], Ba, zeroq, 0, 0, 0);
        f32x4 cB0 = __builtin_amdgcn_mfma_f32_16x16x32_bf16(Ah[0], Bb, zeroq, 0, 0, 0);
        f32x4 cB1 = __builtin_amdgcn_mfma_f32_16x16x32_bf16(Ah[1], Bb, zeroq, 0, 0, 0);
        cA0 = __builtin_amdgcn_mfma_f32_16x16x32_bf16(Al[0], Ba, cA0, 0, 0, 0);
        cA1 = __builtin_amdgcn_mfma_f32_16x16x32_bf16(Al[1], Ba, cA1, 0, 0, 0);
        cB0 = __builtin_amdgcn_mfma_f32_16x16x32_bf16(Al[0], Bb, cB0, 0, 0, 0);
        cB1 = __builtin_amdgcn_mfma_f32_16x16x32_bf16(Al[1], Bb, cB1, 0, 0, 0);
#pragma unroll
        for (int r = 0; r < 4; ++r) {
            rb0[r] = fmaxf(rb0[r], fmaxf(cA0[r], cB0[r]));   // -> v_max3
            rb1[r] = fmaxf(rb1[r], fmaxf(cA1[r], cB1[r]));
        }
        Ba = Na; Bb = Nb;
    }
#undef LDB

    // ---- max over the 16 point-columns (groups of 16 lanes) ----
#pragma unroll
    for (int r = 0; r < 4; ++r) {
        float v0 = rb0[r], v1 = rb1[r];
#pragma unroll
        for (int m = 1; m < 16; m <<= 1) {
            v0 = fmaxf(v0, __shfl_xor(v0, m, 16));
            v1 = fmaxf(v1, __shfl_xor(v1, m, 16));
        }
        rb0[r] = v0; rb1[r] = v1;
    }
    if (n15 == 0) {
        // lane kg*16 holds rows kg*4 + r for both row-tiles
        float* pp = part + (size_t)blockIdx.y * NQ + qblock + w * 32;
#pragma unroll
        for (int r = 0; r < 4; ++r) {
            pp[kg * 4 + r]      = rb0[r];
            pp[16 + kg * 4 + r] = rb1[r];
        }
    }
}

// ---------------------------------------------------------------------------
// Final: reduce SCH chunks, dist2 = ||x||^2 - 2*best, bump.
// ---------------------------------------------------------------------------
__global__ __launch_bounds__(256) void knn_final(const float* __restrict__ x,
                                                 const float* __restrict__ part,
                                                 float* __restrict__ out) {
    const int q = blockIdx.x * 256 + threadIdx.x;
    const float4* xr = (const float4*)(x + (size_t)q * D);
    float4 a = xr[0], b = xr[1], c = xr[2], e = xr[3];
    float x2 = a.x * a.x;
    x2 = fmaf(a.y, a.y, x2); x2 = fmaf(a.z, a.z, x2); x2 = fmaf(a.w, a.w, x2);
    x2 = fmaf(b.x, b.x, x2); x2 = fmaf(b.y, b.y, x2); x2 = fmaf(b.z, b.z, x2); x2 = fmaf(b.w, b.w, x2);
    x2 = fmaf(c.x, c.x, x2); x2 = fmaf(c.y, c.y, x2); x2 = fmaf(c.z, c.z, x2); x2 = fmaf(c.w, c.w, x2);
    x2 = fmaf(e.x, e.x, x2); x2 = fmaf(e.y, e.y, x2); x2 = fmaf(e.z, e.z, x2); x2 = fmaf(e.w, e.w, x2);

    float m0 = -FLT_MAX, m1 = -FLT_MAX, m2 = -FLT_MAX, m3 = -FLT_MAX;
#pragma unroll
    for (int cI = 0; cI < SCH; cI += 4) {
        m0 = fmaxf(m0, part[(size_t)(cI + 0) * NQ + q]);
        m1 = fmaxf(m1, part[(size_t)(cI + 1) * NQ + q]);
        m2 = fmaxf(m2, part[(size_t)(cI + 2) * NQ + q]);
        m3 = fmaxf(m3, part[(size_t)(cI + 3) * NQ + q]);
    }
    float mbest = fmaxf(fmaxf(m0, m1), fmaxf(m2, m3));

    float nn2  = fmaxf(fmaf(-2.f, mbest, x2), 0.f);
    float dist = sqrtf(fmaxf(nn2, 1e-12f));
    float bump = 0.f;
    if (dist < 2.0f) {                      // RADIUS = 2
        float denom = dist * dist - 4.0f;   // d^2 - r^2
        bump = expf(1.0f / denom + 0.25f);  // DECAY/denom + DECAY/r^2
    }
    out[q] = bump;
}

// ===========================================================================
// Fallback (fp32 scalar-pipe path) if workspace is too small for MFMA path.
// ===========================================================================
__global__ __launch_bounds__(256) void neg_half_norms(const float* __restrict__ data,
                                                      float* __restrict__ nhn) {
    const int p = blockIdx.x * 256 + threadIdx.x;
    const float4* r = (const float4*)(data + (size_t)p * D);
    float4 a = r[0], b = r[1], c = r[2], e = r[3];
    float n = a.x * a.x;
    n = fmaf(a.y, a.y, n); n = fmaf(a.z, a.z, n); n = fmaf(a.w, a.w, n);
    n = fmaf(b.x, b.x, n); n = fmaf(b.y, b.y, n); n = fmaf(b.z, b.z, n); n = fmaf(b.w, b.w, n);
    n = fmaf(c.x, c.x, n); n = fmaf(c.y, c.y, n); n = fmaf(c.z, c.z, n); n = fmaf(c.w, c.w, n);
    n = fmaf(e.x, e.x, n); n = fmaf(e.y, e.y, n); n = fmaf(e.z, e.z, n); n = fmaf(e.w, e.w, n);
    nhn[p] = -0.5f * n;
}

__global__ __launch_bounds__(256) void knn_partial_fb(const float* __restrict__ x,
                                                      const float* __restrict__ data,
                                                      const float* __restrict__ nhn,
                                                      float* __restrict__ part, int cp) {
    const int q     = blockIdx.x * 256 + threadIdx.x;
    const int pbase = blockIdx.y * cp;
    const float4* xr = (const float4*)(x + (size_t)q * D);
    const float4 xa = xr[0], xb = xr[1], xc = xr[2], xd = xr[3];
    const float* dp = data + (size_t)pbase * D;
    const float* np = nhn + pbase;
    float best = -FLT_MAX;
    for (int i = 0; i < cp; i += 4) {
#pragma unroll
        for (int j = 0; j < 4; ++j) {
            const float* r  = dp + (size_t)(i + j) * D;
            const float  hn = np[i + j];
            float ca = xa.x * r[0];
            ca = fmaf(xa.y, r[1], ca);  ca = fmaf(xa.z, r[2], ca);  ca = fmaf(xa.w, r[3], ca);
            ca = fmaf(xb.x, r[4], ca);  ca = fmaf(xb.y, r[5], ca);  ca = fmaf(xb.z, r[6], ca);
            ca = fmaf(xb.w, r[7], ca);
            float cb = fmaf(xc.x, r[8], hn);
            cb = fmaf(xc.y, r[9],  cb); cb = fmaf(xc.z, r[10], cb); cb = fmaf(xc.w, r[11], cb);
            cb = fmaf(xd.x, r[12], cb); cb = fmaf(xd.y, r[13], cb); cb = fmaf(xd.z, r[14], cb);
            cb = fmaf(xd.w, r[15], cb);
            best = fmaxf(best, ca + cb);
        }
    }
    part[(size_t)blockIdx.y * NQ + q] = best;
}

__global__ __launch_bounds__(256) void knn_final_fb(const float* __restrict__ x,
                                                    const float* __restrict__ part,
                                                    float* __restrict__ out, int S) {
    const int q = blockIdx.x * 256 + threadIdx.x;
    const float4* xr = (const float4*)(x + (size_t)q * D);
    float4 a = xr[0], b = xr[1], c = xr[2], e = xr[3];
    float x2 = a.x * a.x;
    x2 = fmaf(a.y, a.y, x2); x2 = fmaf(a.z, a.z, x2); x2 = fmaf(a.w, a.w, x2);
    x2 = fmaf(b.x, b.x, x2); x2 = fmaf(b.y, b.y, x2); x2 = fmaf(b.z, b.z, x2); x2 = fmaf(b.w, b.w, x2);
    x2 = fmaf(c.x, c.x, x2); x2 = fmaf(c.y, c.y, x2); x2 = fmaf(c.z, c.z, x2); x2 = fmaf(c.w, c.w, x2);
    x2 = fmaf(e.x, e.x, x2); x2 = fmaf(e.y, e.y, x2); x2 = fmaf(e.z, e.z, x2); x2 = fmaf(e.w, e.w, x2);
    float mb = -FLT_MAX;
    for (int cI = 0; cI < S; ++cI) mb = fmaxf(mb, part[(size_t)cI * NQ + q]);
    float nn2  = fmaxf(fmaf(-2.f, mb, x2), 0.f);
    float dist = sqrtf(fmaxf(nn2, 1e-12f));
    float bump = 0.f;
    if (dist < 2.0f) {
        float denom = dist * dist - 4.0f;
        bump = expf(1.0f / denom + 0.25f);
    }
    out[q] = bump;
}

extern "C" void kernel_launch(void* const* d_in, const int* in_sizes, int n_in,
                              void* d_out, int out_size, void* d_ws, size_t ws_size,
                              hipStream_t stream) {
    const float* x    = (const float*)d_in[0];   // [2048,16] fp32
    const float* data = (const float*)d_in[1];   // [65536,16] fp32
    float* out = (float*)d_out;                  // [2048] fp32

    // ws layout (bytes):
    //   Ppk  [0, 4 MiB)       SCH chunks x 32 KB (K=32 packed, lane order)
    //   part [4 MiB, +1 MiB)  SCH*NQ fp32
    const size_t off_part = (size_t)SCH * CHUNK_B;           // 4194304
    const size_t needed   = off_part + (size_t)SCH * NQ * 4; // 5242880

    if (ws_size >= needed) {
        unsigned char* Ppk = (unsigned char*)d_ws;
        float* part = (float*)((char*)d_ws + off_part);

        pack_data<<<ND / 256, 256, 0, stream>>>(data, Ppk);
        knn_mfma<<<dim3(NQ / 128, SCH), 256, 0, stream>>>(x, Ppk, part);
        knn_final<<<NQ / 256, 256, 0, stream>>>(x, part, out);
    } else {
        int S = 32;
        while (S > 1 && (size_t)(ND + S * NQ) * sizeof(float) > ws_size) S >>= 1;
        const int cp = ND / S;
        float* nhn  = (float*)d_ws;
        float* part = (float*)d_ws + ND;
        neg_half_norms<<<ND / 256, 256, 0, stream>>>(data, nhn);
        knn_partial_fb<<<dim3(NQ / 256, S), 256, 0, stream>>>(x, data, nhn, part, cp);
        knn_final_fb<<<NQ / 256, 256, 0, stream>>>(x, part, out, S);
    }
}